// Round 10
// baseline (74.182 us; speedup 1.0000x reference)
//
#include <hip/hip_runtime.h>
#include <math.h>

#define NG 2048
#define IMG_W 128
#define IMG_H 128
#define NPIX (IMG_W * IMG_H)
#define ALPHA_MIN (1.0f / 255.0f)
#define NQ 8                  // z-segments per tile
#define QSEG (NG / NQ)        // 256 gaussians per segment = 4 waves x 64

// ws layout:
//   [0, 96K)      : float aos[2048][12] z-sorted params:
//                   (px, py, Lc, A) (B, C, op, cr) (cg, cb, BoA, BoC)
//                   Lc = ln(255*op)+0.05 cull threshold (-1 if invalid);
//                   BoA = B/A, BoC = B/C for the edge-min cull test.
//   [96K, 96K+2M) : float partial[NQ*4][16384]  (q*4+ch)*16384 + tile*64+lane
//
// Session knowledge: harness base ~57us (R4/R5); graph nodes ~free (R2/R6);
// cooperative launch ~30us/node (R3); device-scope fences ~40us at wave
// scale (R4/R5) -> kernel-boundary coherence only. R8 probe: render was
// issue-bound; R9 exact-ellipse cull + z-split load balance. R10: halve
// prep's serial f64 chain (f32 log + f32 conic divisions; f64 kept for the
// radii ceil path), 8-way z-split render (exact, no early-out approx).

// ---------------------------------------------------------------------------
// 256 blocks x 256 threads. Stable rank (z asc, ties by index == stable
// argsort): 32 threads per gaussian scan 64 z's each from LDS (stride-32 =
// conflict-free), shfl-reduce width 32. Then 8 leader threads per block do
// the projection/conic and scatter the z-sorted AoS.
__global__ void __launch_bounds__(256) prep_kernel(const float* __restrict__ means,
                                                   const float* __restrict__ colors,
                                                   const float* __restrict__ opac,
                                                   const float* __restrict__ cov3,
                                                   float* __restrict__ radii_out,
                                                   float* __restrict__ aos) {
    __shared__ float zs[NG];          // 8 KB
    __shared__ int   rankv[8];

    const int t = threadIdx.x;
    const int b = blockIdx.x;

    for (int k = t; k < NG; k += 256) zs[k] = means[k * 3 + 2];
    __syncthreads();

    const int g   = b * 8 + (t >> 5);   // this thread-group's gaussian
    const int sub = t & 31;
    const float zg = zs[g];
    int cnt = 0;
#pragma unroll 8
    for (int k = 0; k < 64; ++k) {
        const int j = sub + 32 * k;
        const float zj = zs[j];
        cnt += (zj < zg || (zj == zg && j < g)) ? 1 : 0;
    }
#pragma unroll
    for (int d = 16; d; d >>= 1) cnt += __shfl_down(cnt, d, 32);
    if (sub == 0) rankv[t >> 5] = cnt;
    __syncthreads();

    if (t < 8) {
        const int i = b * 8 + t;
        // ---- f64 only for the radii path (ceil() boundary sensitivity) ----
        const double x = means[i * 3 + 0];
        const double y = means[i * 3 + 1];
        const double z = means[i * 3 + 2];
        const double inv_z = 1.0 / z;
        const double fx = 128.0, fy = 128.0, lim = 0.65;  // W/(2*tanfov), 1.3*tanfov
        const double px = fx * x * inv_z + 64.0;
        const double py = fy * y * inv_z + 64.0;
        double tx = x * inv_z; tx = fmin(fmax(tx, -lim), lim); tx *= z;
        double ty = y * inv_z; ty = fmin(fmax(ty, -lim), lim); ty *= z;
        const double xx = cov3[i * 6 + 0], xy = cov3[i * 6 + 1], xz = cov3[i * 6 + 2];
        const double yy = cov3[i * 6 + 3], yz = cov3[i * 6 + 4], zz = cov3[i * 6 + 5];
        const double J00 = fx * inv_z, J02 = -fx * tx * inv_z * inv_z;
        const double J11 = fy * inv_z, J12 = -fy * ty * inv_z * inv_z;
        const double M00 = J00 * xx + J02 * xz;
        const double M01 = J00 * xy + J02 * yz;
        const double M02 = J00 * xz + J02 * zz;
        const double M11 = J11 * yy + J12 * yz;
        const double M12 = J11 * yz + J12 * zz;
        const double a  = M00 * J00 + M02 * J02 + 0.3;
        const double bb = M01 * J11 + M02 * J12;  // cov2[0,1]
        const double c  = M11 * J11 + M12 * J12 + 0.3;
        const double det = a * c - bb * bb;
        const double mid = 0.5 * (a + c);
        const double lam1 = mid + sqrt(fmax(0.1, mid * mid - det));
        const bool valid = (z > 0.2) && (det > 0.0);
        radii_out[i] = valid ? (float)ceil(3.0 * sqrt(lam1)) : 0.0f;

        // ---- f32 for everything feeding the image/cull (ref is f32 too) ---
        const float af = (float)a, bf = (float)bb, cf = (float)c;
        const float inv_det_f = 1.0f / (float)det;
        const float op = opac[i];
        // Cull: keep (gaussian,tile) iff min over tile rect of
        // 0.5 d^T Sigma^-1 d <= Lc = ln(255*op)+0.05 (margin >> f32 error).
        float Lc = -1.0f;
        if (valid) {
            const float L = logf(255.0f * op);
            Lc = (L > 0.0f) ? (L + 0.05f) : -1.0f;
        }
        const int r = rankv[t];
        float4* dst = (float4*)(aos + r * 12);
        dst[0] = make_float4((float)px, (float)py, Lc, cf * inv_det_f);
        dst[1] = make_float4(-bf * inv_det_f, af * inv_det_f, op,
                             colors[i * 3 + 0]);
        dst[2] = make_float4(colors[i * 3 + 1], colors[i * 3 + 2],
                             -bf / cf, -bf / af);  // B/A, B/C
    }
}

// ---------------------------------------------------------------------------
// 2048 blocks x 256 threads. Block = (tile, z-eighth): tile = bid>>3 is an
// 8x8 pixel tile, q = bid&7 selects gaussians [q*256, q*256+256); the 4
// waves take 64 each (z-contiguous, single chunk -> no loop, no early-out
// approximation). Exact ellipse-vs-rect cull per lane, ballot, readlane hit
// loop. Block merges its 4 waves -> per-(tile,q) partial (R,G,B,T).
__global__ void __launch_bounds__(256) render_kernel(const float* __restrict__ aos,
                                                     float* __restrict__ partial) {
    __shared__ float part[4][4][64];
    const int t = threadIdx.x;
    const int lane = t & 63;
    const int wave = t >> 6;
    const int tile = blockIdx.x >> 3;
    const int q    = blockIdx.x & 7;
    const int tile_x = (tile & 15) * 8;
    const int tile_y = (tile >> 4) * 8;
    const float pxf = (float)(tile_x + (lane & 7));
    const float pyf = (float)(tile_y + (lane >> 3));
    const float tx0 = (float)tile_x, tx1 = (float)(tile_x + 7);
    const float ty0 = (float)tile_y, ty1 = (float)(tile_y + 7);

    const float4* __restrict__ av = (const float4*)aos;

    float T = 1.0f, accr = 0.0f, accg = 0.0f, accb = 0.0f;

    const int g = q * QSEG + wave * 64 + lane;
    const float4 a0 = av[g * 3 + 0];
    const float4 a1 = av[g * 3 + 1];
    const float4 a2 = av[g * 3 + 2];

    // ---- exact ellipse-vs-rect cull (lane-parallel, one gaussian/lane).
    const float lx = a0.x - tx1, hx = a0.x - tx0;
    const float ly = a0.y - ty1, hy = a0.y - ty0;
    const float hA = 0.5f * a0.w, hC = 0.5f * a1.y;
    const float Bq = a1.x, BoA = a2.z, BoC = a2.w;
    const bool inside = (lx <= 0.0f) & (hx >= 0.0f) & (ly <= 0.0f) & (hy >= 0.0f);
    const float dy1 = fminf(fmaxf(-BoC * lx, ly), hy);
    const float q1  = hA * lx * lx + Bq * lx * dy1 + hC * dy1 * dy1;
    const float dy2 = fminf(fmaxf(-BoC * hx, ly), hy);
    const float q2  = hA * hx * hx + Bq * hx * dy2 + hC * dy2 * dy2;
    const float dx3 = fminf(fmaxf(-BoA * ly, lx), hx);
    const float q3  = hC * ly * ly + Bq * dx3 * ly + hA * dx3 * dx3;
    const float dx4 = fminf(fmaxf(-BoA * hy, lx), hx);
    const float q4  = hC * hy * hy + Bq * dx4 * hy + hA * dx4 * dx4;
    float qm = fminf(fminf(q1, q2), fminf(q3, q4));
    if (inside) qm = 0.0f;
    unsigned long long m = __ballot(qm <= a0.z);   // q_min <= Lc

#define RL(x, jj) __int_as_float(__builtin_amdgcn_readlane(__float_as_int(x), jj))
    while (m) {
        const int j = __builtin_ctzll(m);
        m &= (m - 1);
        const float cx = RL(a0.x, j), cy = RL(a0.y, j);
        const float A = RL(a0.w, j), B = RL(a1.x, j), C = RL(a1.y, j);
        const float op = RL(a1.z, j);
        const float cr = RL(a1.w, j), cg = RL(a2.x, j), cb = RL(a2.y, j);
        const float dx = cx - pxf, dy = cy - pyf;
        const float power = -0.5f * (A * dx * dx + C * dy * dy) - B * dx * dy;
        const float alpha = fminf(0.99f, op * __expf(power));
        const bool keep = (power <= 0.0f) & (alpha >= ALPHA_MIN);
        const float ae = keep ? alpha : 0.0f;
        const float w = ae * T;
        accr = fmaf(w, cr, accr);
        accg = fmaf(w, cg, accg);
        accb = fmaf(w, cb, accb);
        T = fmaf(-ae, T, T);
    }
#undef RL

    // merge this block's 4 waves (z-ordered), store per-(tile,q) partial
    part[wave][0][lane] = accr;
    part[wave][1][lane] = accg;
    part[wave][2][lane] = accb;
    part[wave][3][lane] = T;
    __syncthreads();
    if (wave == 0) {
        float R = part[0][0][lane], G = part[0][1][lane], Bc = part[0][2][lane];
        float Tt = part[0][3][lane];
#pragma unroll
        for (int s = 1; s < 4; ++s) {
            R  = fmaf(Tt, part[s][0][lane], R);
            G  = fmaf(Tt, part[s][1][lane], G);
            Bc = fmaf(Tt, part[s][2][lane], Bc);
            Tt *= part[s][3][lane];
        }
        const int base = tile * 64 + lane;
        partial[(q * 4 + 0) * NPIX + base] = R;
        partial[(q * 4 + 1) * NPIX + base] = G;
        partial[(q * 4 + 2) * NPIX + base] = Bc;
        partial[(q * 4 + 3) * NPIX + base] = Tt;
    }
}

// ---------------------------------------------------------------------------
// 64 blocks x 256 threads: one thread per pixel. Combine the NQ z-segment
// partials front-to-back (exact reassociation), add bg term, write image.
__global__ void __launch_bounds__(256) merge_kernel(const float* __restrict__ partial,
                                                    const float* __restrict__ bgp,
                                                    float* __restrict__ out) {
    const int id = blockIdx.x * 256 + threadIdx.x;   // tile*64 + lane ordering
    const int tile = id >> 6, lane = id & 63;
    float R  = partial[0 * NPIX + id];
    float G  = partial[1 * NPIX + id];
    float Bc = partial[2 * NPIX + id];
    float T  = partial[3 * NPIX + id];
#pragma unroll
    for (int s = 1; s < NQ; ++s) {
        R  = fmaf(T, partial[(s * 4 + 0) * NPIX + id], R);
        G  = fmaf(T, partial[(s * 4 + 1) * NPIX + id], G);
        Bc = fmaf(T, partial[(s * 4 + 2) * NPIX + id], Bc);
        T *= partial[(s * 4 + 3) * NPIX + id];
    }
    const int pix = (((tile >> 4) * 8) + (lane >> 3)) * IMG_W
                    + ((tile & 15) * 8) + (lane & 7);
    out[pix]            = fmaf(T, bgp[0], R);
    out[pix + NPIX]     = fmaf(T, bgp[1], G);
    out[pix + 2 * NPIX] = fmaf(T, bgp[2], Bc);
}

// ---------------------------------------------------------------------------
extern "C" void kernel_launch(void* const* d_in, const int* in_sizes, int n_in,
                              void* d_out, int out_size, void* d_ws, size_t ws_size,
                              hipStream_t stream) {
    const float* means  = (const float*)d_in[0];  // (N,3)
    const float* colors = (const float*)d_in[1];  // (N,3)
    const float* opac   = (const float*)d_in[2];  // (N,1)
    const float* cov3   = (const float*)d_in[3];  // (N,6)
    const float* bg     = (const float*)d_in[4];  // (3,)
    float* out = (float*)d_out;  // img (3*128*128) then radii (2048) as float
    float* aos     = (float*)d_ws;
    float* partial = (float*)((char*)d_ws + 96 * 1024);

    prep_kernel<<<256, 256, 0, stream>>>(means, colors, opac, cov3,
                                         out + 3 * NPIX, aos);
    render_kernel<<<2048, 256, 0, stream>>>(aos, partial);
    merge_kernel<<<64, 256, 0, stream>>>(partial, bg, out);
}

// Round 11
// 71.676 us; speedup vs baseline: 1.0350x; 1.0350x over previous
//
#include <hip/hip_runtime.h>
#include <math.h>

#define NG 2048
#define IMG_W 128
#define IMG_H 128
#define NPIX (IMG_W * IMG_H)
#define ALPHA_MIN (1.0f / 255.0f)
#define NSEG 16               // z-segments per tile (one per wave)
#define SEG (NG / NSEG)       // 128 gaussians per segment = 2 chunks of 64

// ws layout: [0, 96K) float aos[2048][12] z-sorted params:
//   (px, py, Lc, A) (B, C, op, cr) (cg, cb, BoA, BoC)
//   Lc = ln(255*op)+0.05 cull threshold (-1 if invalid);
//   BoA = B/A, BoC = B/C for the edge-min cull test.
//
// Session knowledge: harness base ~57us (R4/R5); cooperative launch ~30us
// as a graph node (R3); device-scope fences ~40us at wave scale (R4/R5) ->
// kernel-boundary coherence only. R10: work reduction neutral -> residual is
// per-kernel fixed cost (dispatch + SCLK ramp). R11: 2 kernels, 512 total
// workgroups, no partial round-trip; exact arithmetic (R10 hit absmax 0.0).

// ---------------------------------------------------------------------------
// 256 blocks x 256 threads. Stable rank (z asc, ties by index == stable
// argsort): 32 threads per gaussian scan 64 z's each from LDS (stride-32 =
// conflict-free), shfl-reduce width 32. Then 8 leader threads per block do
// the projection/conic and scatter the z-sorted AoS. f64 only on the radii
// path (ceil() boundary sensitivity); f32 for image/cull params.
__global__ void __launch_bounds__(256) prep_kernel(const float* __restrict__ means,
                                                   const float* __restrict__ colors,
                                                   const float* __restrict__ opac,
                                                   const float* __restrict__ cov3,
                                                   float* __restrict__ radii_out,
                                                   float* __restrict__ aos) {
    __shared__ float zs[NG];          // 8 KB
    __shared__ int   rankv[8];

    const int t = threadIdx.x;
    const int b = blockIdx.x;

    for (int k = t; k < NG; k += 256) zs[k] = means[k * 3 + 2];
    __syncthreads();

    const int g   = b * 8 + (t >> 5);   // this thread-group's gaussian
    const int sub = t & 31;
    const float zg = zs[g];
    int cnt = 0;
#pragma unroll 8
    for (int k = 0; k < 64; ++k) {
        const int j = sub + 32 * k;
        const float zj = zs[j];
        cnt += (zj < zg || (zj == zg && j < g)) ? 1 : 0;
    }
#pragma unroll
    for (int d = 16; d; d >>= 1) cnt += __shfl_down(cnt, d, 32);
    if (sub == 0) rankv[t >> 5] = cnt;
    __syncthreads();

    if (t < 8) {
        const int i = b * 8 + t;
        // ---- f64 only for the radii path ----
        const double x = means[i * 3 + 0];
        const double y = means[i * 3 + 1];
        const double z = means[i * 3 + 2];
        const double inv_z = 1.0 / z;
        const double fx = 128.0, fy = 128.0, lim = 0.65;  // W/(2*tanfov), 1.3*tanfov
        const double px = fx * x * inv_z + 64.0;
        const double py = fy * y * inv_z + 64.0;
        double tx = x * inv_z; tx = fmin(fmax(tx, -lim), lim); tx *= z;
        double ty = y * inv_z; ty = fmin(fmax(ty, -lim), lim); ty *= z;
        const double xx = cov3[i * 6 + 0], xy = cov3[i * 6 + 1], xz = cov3[i * 6 + 2];
        const double yy = cov3[i * 6 + 3], yz = cov3[i * 6 + 4], zz = cov3[i * 6 + 5];
        const double J00 = fx * inv_z, J02 = -fx * tx * inv_z * inv_z;
        const double J11 = fy * inv_z, J12 = -fy * ty * inv_z * inv_z;
        const double M00 = J00 * xx + J02 * xz;
        const double M01 = J00 * xy + J02 * yz;
        const double M02 = J00 * xz + J02 * zz;
        const double M11 = J11 * yy + J12 * yz;
        const double M12 = J11 * yz + J12 * zz;
        const double a  = M00 * J00 + M02 * J02 + 0.3;
        const double bb = M01 * J11 + M02 * J12;  // cov2[0,1]
        const double c  = M11 * J11 + M12 * J12 + 0.3;
        const double det = a * c - bb * bb;
        const double mid = 0.5 * (a + c);
        const double lam1 = mid + sqrt(fmax(0.1, mid * mid - det));
        const bool valid = (z > 0.2) && (det > 0.0);
        radii_out[i] = valid ? (float)ceil(3.0 * sqrt(lam1)) : 0.0f;

        // ---- f32 for everything feeding the image/cull (ref is f32 too) ---
        const float af = (float)a, bf = (float)bb, cf = (float)c;
        const float inv_det_f = 1.0f / (float)det;
        const float op = opac[i];
        // Cull: keep (gaussian,tile) iff min over tile rect of
        // 0.5 d^T Sigma^-1 d <= Lc = ln(255*op)+0.05 (margin >> f32 error).
        float Lc = -1.0f;
        if (valid) {
            const float L = logf(255.0f * op);
            Lc = (L > 0.0f) ? (L + 0.05f) : -1.0f;
        }
        const int r = rankv[t];
        float4* dst = (float4*)(aos + r * 12);
        dst[0] = make_float4((float)px, (float)py, Lc, cf * inv_det_f);
        dst[1] = make_float4(-bf * inv_det_f, af * inv_det_f, op,
                             colors[i * 3 + 0]);
        dst[2] = make_float4(colors[i * 3 + 1], colors[i * 3 + 2],
                             -bf / cf, -bf / af);  // B/A, B/C
    }
}

// ---------------------------------------------------------------------------
// 256 blocks x 1024 threads (16 waves = 4/SIMD). Block = one 8x8 pixel tile;
// wave w composites z-segment [w*128, w*128+128) in 2 chunks of 64. Exact
// ellipse-vs-rect cull per lane, ballot, readlane hit loop (no memory ops
// per hit). LDS merge of the 16 z-segments (exact reassociation):
//   img = sum_s (prod_{s'<s} T_s') * acc_s ,  T = prod_s T_s.
// No early-out: bit-exact vs reference (R10 absmax 0.0).
__global__ void __launch_bounds__(1024) render_kernel(const float* __restrict__ aos,
                                                      const float* __restrict__ bgp,
                                                      float* __restrict__ out) {
    __shared__ float part[NSEG][4][64];
    const int t = threadIdx.x;
    const int lane = t & 63;
    const int wave = t >> 6;
    const int tile = blockIdx.x;
    const int tile_x = (tile & 15) * 8;
    const int tile_y = (tile >> 4) * 8;
    const float pxf = (float)(tile_x + (lane & 7));
    const float pyf = (float)(tile_y + (lane >> 3));
    const float tx0 = (float)tile_x, tx1 = (float)(tile_x + 7);
    const float ty0 = (float)tile_y, ty1 = (float)(tile_y + 7);

    const float4* __restrict__ av = (const float4*)aos;

    float T = 1.0f, accr = 0.0f, accg = 0.0f, accb = 0.0f;

#define RL(x, jj) __int_as_float(__builtin_amdgcn_readlane(__float_as_int(x), jj))
#pragma unroll
    for (int c = 0; c < SEG / 64; ++c) {
        const int g = wave * SEG + c * 64 + lane;
        const float4 a0 = av[g * 3 + 0];
        const float4 a1 = av[g * 3 + 1];
        const float4 a2 = av[g * 3 + 2];

        // ---- exact ellipse-vs-rect cull (lane-parallel, one gaussian/lane).
        const float lx = a0.x - tx1, hx = a0.x - tx0;
        const float ly = a0.y - ty1, hy = a0.y - ty0;
        const float hA = 0.5f * a0.w, hC = 0.5f * a1.y;
        const float Bq = a1.x, BoA = a2.z, BoC = a2.w;
        const bool inside = (lx <= 0.0f) & (hx >= 0.0f) & (ly <= 0.0f) & (hy >= 0.0f);
        const float dy1 = fminf(fmaxf(-BoC * lx, ly), hy);
        const float q1  = hA * lx * lx + Bq * lx * dy1 + hC * dy1 * dy1;
        const float dy2 = fminf(fmaxf(-BoC * hx, ly), hy);
        const float q2  = hA * hx * hx + Bq * hx * dy2 + hC * dy2 * dy2;
        const float dx3 = fminf(fmaxf(-BoA * ly, lx), hx);
        const float q3  = hC * ly * ly + Bq * dx3 * ly + hA * dx3 * dx3;
        const float dx4 = fminf(fmaxf(-BoA * hy, lx), hx);
        const float q4  = hC * hy * hy + Bq * dx4 * hy + hA * dx4 * dx4;
        float qm = fminf(fminf(q1, q2), fminf(q3, q4));
        if (inside) qm = 0.0f;
        unsigned long long m = __ballot(qm <= a0.z);   // q_min <= Lc

        while (m) {
            const int j = __builtin_ctzll(m);
            m &= (m - 1);
            const float cx = RL(a0.x, j), cy = RL(a0.y, j);
            const float A = RL(a0.w, j), B = RL(a1.x, j), C = RL(a1.y, j);
            const float op = RL(a1.z, j);
            const float cr = RL(a1.w, j), cg = RL(a2.x, j), cb = RL(a2.y, j);
            const float dx = cx - pxf, dy = cy - pyf;
            const float power = -0.5f * (A * dx * dx + C * dy * dy) - B * dx * dy;
            const float alpha = fminf(0.99f, op * __expf(power));
            const bool keep = (power <= 0.0f) & (alpha >= ALPHA_MIN);
            const float ae = keep ? alpha : 0.0f;
            const float w = ae * T;
            accr = fmaf(w, cr, accr);
            accg = fmaf(w, cg, accg);
            accb = fmaf(w, cb, accb);
            T = fmaf(-ae, T, T);
        }
    }
#undef RL

    // merge the 16 z-segments, front to back (exact reassociation)
    part[wave][0][lane] = accr;
    part[wave][1][lane] = accg;
    part[wave][2][lane] = accb;
    part[wave][3][lane] = T;
    __syncthreads();
    if (wave == 0) {
        float R = part[0][0][lane], G = part[0][1][lane], Bc = part[0][2][lane];
        float Tt = part[0][3][lane];
#pragma unroll
        for (int s = 1; s < NSEG; ++s) {
            R  = fmaf(Tt, part[s][0][lane], R);
            G  = fmaf(Tt, part[s][1][lane], G);
            Bc = fmaf(Tt, part[s][2][lane], Bc);
            Tt *= part[s][3][lane];
        }
        const int pix = (tile_y + (lane >> 3)) * IMG_W + tile_x + (lane & 7);
        out[pix]            = fmaf(Tt, bgp[0], R);
        out[pix + NPIX]     = fmaf(Tt, bgp[1], G);
        out[pix + 2 * NPIX] = fmaf(Tt, bgp[2], Bc);
    }
}

// ---------------------------------------------------------------------------
extern "C" void kernel_launch(void* const* d_in, const int* in_sizes, int n_in,
                              void* d_out, int out_size, void* d_ws, size_t ws_size,
                              hipStream_t stream) {
    const float* means  = (const float*)d_in[0];  // (N,3)
    const float* colors = (const float*)d_in[1];  // (N,3)
    const float* opac   = (const float*)d_in[2];  // (N,1)
    const float* cov3   = (const float*)d_in[3];  // (N,6)
    const float* bg     = (const float*)d_in[4];  // (3,)
    float* out = (float*)d_out;  // img (3*128*128) then radii (2048) as float
    float* aos = (float*)d_ws;

    prep_kernel<<<256, 256, 0, stream>>>(means, colors, opac, cov3,
                                         out + 3 * NPIX, aos);
    render_kernel<<<256, 1024, 0, stream>>>(aos, bg, out);
}